// Round 1
// baseline (650.326 us; speedup 1.0000x reference)
//
#include <hip/hip_runtime.h>
#include <cmath>

// BlockwiseEarlyExitMamba: output depends only on feat[:,31,:] -> compute T=32 tokens.
#define BATCH 16
#define TT 32
#define NTOK 512   // BATCH*TT
#define DM 256
#define DI 512

__device__ __forceinline__ float silu_(float x){ return x / (1.f + expf(-x)); }

// sum of (a) and (b) over a 256-thread block (4 waves of 64)
__device__ __forceinline__ void block_sum2_(float a, float b, float* red, float& oa, float& ob){
  #pragma unroll
  for (int off = 32; off > 0; off >>= 1){
    a += __shfl_down(a, off, 64);
    b += __shfl_down(b, off, 64);
  }
  __syncthreads();                 // protect red reuse across calls
  int lane = threadIdx.x & 63;
  int w    = threadIdx.x >> 6;
  if (lane == 0){ red[2*w] = a; red[2*w+1] = b; }
  __syncthreads();
  oa = red[0] + red[2] + red[4] + red[6];
  ob = red[1] + red[3] + red[5] + red[7];
}

__global__ __launch_bounds__(256)
void k_frontend(const float* __restrict__ x,
                const float* __restrict__ ep, const float* __restrict__ ef,
                const float* __restrict__ ed,
                const float* __restrict__ plw, const float* __restrict__ plb,
                const float* __restrict__ piw, const float* __restrict__ pib,
                const float* __restrict__ fw,  const float* __restrict__ fb,
                const float* __restrict__ tg,  const float* __restrict__ tb,
                float* __restrict__ feat)
{
  __shared__ float cat[136];
  __shared__ float red[8];
  int p = blockIdx.x;
  int b = p >> 5, t = p & 31;
  const float* xr = x + ((size_t)(b * 1024 + t)) * 5;   // full-seqlen input, early-exit at T=32
  int c = threadIdx.x;
  if (c < 136){
    float v;
    if      (c < 32){ int i = __float2int_rz(xr[0]); i = min(max(i,0),255); v = ep[i*32 + c]; }
    else if (c < 64){ int j = c-32; v = xr[1]*plw[j] + plb[j]; }
    else if (c < 96){ int j = c-64; int i = __float2int_rz(xr[2]); i = min(max(i,0),63); v = ef[i*32 + j]; }
    else if (c < 128){ int j = c-96; v = xr[3]*piw[j] + pib[j]; }
    else            { int j = c-128; int i = __float2int_rz(xr[4]); i = min(max(i,0),1); v = ed[i*8 + j]; }
    cat[c] = v;
  }
  __syncthreads();
  const float* wr = fw + (size_t)c * 136;
  float acc = fb[c];
  #pragma unroll 8
  for (int j = 0; j < 136; ++j) acc += cat[j] * wr[j];
  float s, sq;
  block_sum2_(acc, acc*acc, red, s, sq);
  float m   = s * (1.f/256.f);
  float var = sq * (1.f/256.f) - m*m;
  float r   = rsqrtf(var + 1e-5f);
  feat[p*DM + c] = (acc - m) * r * tg[c] + tb[c];
}

__global__ __launch_bounds__(256)
void k_inproj(const float* __restrict__ feat, const float* __restrict__ w,
              float* __restrict__ xz)
{
  __shared__ float f[256];
  int p = blockIdx.x;
  f[threadIdx.x] = feat[p*DM + threadIdx.x];
  __syncthreads();
  #pragma unroll
  for (int o = 0; o < 4; ++o){
    int cidx = o*256 + threadIdx.x;
    const float4* wr = (const float4*)(w + (size_t)cidx*256);
    float acc = 0.f;
    #pragma unroll 4
    for (int j = 0; j < 64; ++j){
      float4 wv = wr[j];
      acc += f[4*j+0]*wv.x + f[4*j+1]*wv.y + f[4*j+2]*wv.z + f[4*j+3]*wv.w;
    }
    xz[(size_t)p*1024 + cidx] = acc;
  }
}

__global__ __launch_bounds__(512)
void k_conv(const float* __restrict__ xz,
            const float* __restrict__ cw, const float* __restrict__ cb,
            const float* __restrict__ xpw,
            const float* __restrict__ dtw, const float* __restrict__ dtb,
            float* __restrict__ xc, float* __restrict__ dtv,
            float* __restrict__ Bm, float* __restrict__ Cm)
{
  __shared__ float sxc[512];
  __shared__ float sdtr[16];
  int p = blockIdx.x;
  int b = p >> 5, t = p & 31;
  int d = threadIdx.x;
  // causal depthwise conv, kernel 4, left pad 3: out[t] = sum_k w[k]*in[t-3+k]
  float acc = cb[d];
  #pragma unroll
  for (int k = 0; k < 4; ++k){
    int tt = t - 3 + k;
    if (tt >= 0) acc += cw[d*4 + k] * xz[((size_t)(b*TT + tt))*1024 + d];
  }
  float v = silu_(acc);
  sxc[d] = v;
  xc[(size_t)p*DI + d] = v;
  __syncthreads();
  // x_proj: 48 outputs = [dtr(16) | B(16) | C(16)], each a 512-dot
  if (d < 48){
    const float4* wr = (const float4*)(xpw + (size_t)d*512);
    float a = 0.f;
    #pragma unroll 4
    for (int j = 0; j < 128; ++j){
      float4 wv = wr[j];
      a += sxc[4*j+0]*wv.x + sxc[4*j+1]*wv.y + sxc[4*j+2]*wv.z + sxc[4*j+3]*wv.w;
    }
    if      (d < 16) sdtr[d] = a;
    else if (d < 32) Bm[p*16 + (d-16)] = a;
    else             Cm[p*16 + (d-32)] = a;
  }
  __syncthreads();
  // dt = softplus(dtr @ dtw.T + dtb)  (stable form)
  float a = dtb[d];
  const float* wr = dtw + d*16;
  #pragma unroll
  for (int r = 0; r < 16; ++r) a += sdtr[r]*wr[r];
  dtv[(size_t)p*DI + d] = fmaxf(a, 0.f) + log1pf(expf(-fabsf(a)));
}

__global__ __launch_bounds__(256)
void k_scan(const float* __restrict__ dtv, const float* __restrict__ xc,
            const float* __restrict__ Bm, const float* __restrict__ Cm,
            const float* __restrict__ alog, const float* __restrict__ dprm,
            const float* __restrict__ xz, float* __restrict__ yg)
{
  int tid = blockIdx.x*256 + threadIdx.x;   // 8192 threads = 16 b * 512 d
  int b = tid >> 9, d = tid & 511;
  float A[16], h[16];
  #pragma unroll
  for (int n = 0; n < 16; ++n){ A[n] = -expf(alog[d*16 + n]); h[n] = 0.f; }
  float Dp = dprm[d];
  for (int t = 0; t < TT; ++t){
    int p = b*TT + t;
    float dt = dtv[(size_t)p*DI + d];
    float xv = xc[(size_t)p*DI + d];
    float dx = dt * xv;
    float y = 0.f;
    #pragma unroll
    for (int n = 0; n < 16; ++n){
      h[n] = expf(dt*A[n])*h[n] + dx*Bm[p*16 + n];
      y   += h[n]*Cm[p*16 + n];
    }
    y += Dp * xv;
    float z = xz[(size_t)p*1024 + 512 + d];
    yg[(size_t)p*DI + d] = y * silu_(z);
  }
}

__global__ __launch_bounds__(256)
void k_outln(const float* __restrict__ yg, const float* __restrict__ w,
             const float* __restrict__ ng, const float* __restrict__ nb,
             float* __restrict__ feat)
{
  __shared__ float sy[512];
  __shared__ float red[8];
  int p = blockIdx.x;
  int c = threadIdx.x;
  sy[c]       = yg[(size_t)p*DI + c];
  sy[c + 256] = yg[(size_t)p*DI + 256 + c];
  __syncthreads();
  const float4* wr = (const float4*)(w + (size_t)c*512);
  float acc = feat[p*DM + c];              // residual
  #pragma unroll 4
  for (int j = 0; j < 128; ++j){
    float4 wv = wr[j];
    acc += sy[4*j+0]*wv.x + sy[4*j+1]*wv.y + sy[4*j+2]*wv.z + sy[4*j+3]*wv.w;
  }
  float s, sq;
  block_sum2_(acc, acc*acc, red, s, sq);
  float m   = s*(1.f/256.f);
  float var = sq*(1.f/256.f) - m*m;
  float r   = rsqrtf(var + 1e-5f);
  feat[p*DM + c] = (acc - m)*r*ng[c] + nb[c];
}

__global__ __launch_bounds__(128)
void k_cls(const float* __restrict__ feat,
           const float* __restrict__ w1, const float* __restrict__ b1,
           const float* __restrict__ w2, const float* __restrict__ b2,
           float* __restrict__ out)
{
  __shared__ float h[256];
  __shared__ float h1[128];
  int b = blockIdx.x;
  int tid = threadIdx.x;
  const float* fr = feat + ((size_t)(b*TT + 31))*DM;   // token 31
  h[tid]       = fr[tid];
  h[tid + 128] = fr[tid + 128];
  __syncthreads();
  float a = b1[tid];
  const float* wr = w1 + (size_t)tid*256;
  #pragma unroll 8
  for (int j = 0; j < 256; ++j) a += h[j]*wr[j];
  h1[tid] = fmaxf(a, 0.f);
  __syncthreads();
  if (tid < 2){
    float a2 = b2[tid];
    const float* wr2 = w2 + (size_t)tid*128;
    #pragma unroll 8
    for (int j = 0; j < 128; ++j) a2 += h1[j]*wr2[j];
    out[b*2 + tid] = a2;
  }
}

extern "C" void kernel_launch(void* const* d_in, const int* in_sizes, int n_in,
                              void* d_out, int out_size, void* d_ws, size_t ws_size,
                              hipStream_t stream)
{
  const float* x   = (const float*)d_in[0];
  const float* ep  = (const float*)d_in[1];
  const float* ef  = (const float*)d_in[2];
  const float* ed  = (const float*)d_in[3];
  const float* plw = (const float*)d_in[4];
  const float* plb = (const float*)d_in[5];
  const float* piw = (const float*)d_in[6];
  const float* pib = (const float*)d_in[7];
  const float* fw  = (const float*)d_in[8];
  const float* fb  = (const float*)d_in[9];
  const float* tg  = (const float*)d_in[10];
  const float* tb  = (const float*)d_in[11];
  const float* ng  = (const float*)d_in[12];
  const float* nb  = (const float*)d_in[13];
  const float* ipw = (const float*)d_in[14];
  const float* cw  = (const float*)d_in[15];
  const float* cb  = (const float*)d_in[16];
  const float* xpw = (const float*)d_in[17];
  const float* dtw = (const float*)d_in[18];
  const float* dtb = (const float*)d_in[19];
  const float* alog= (const float*)d_in[20];
  const float* dpr = (const float*)d_in[21];
  const float* opw = (const float*)d_in[22];
  const float* w1  = (const float*)d_in[23];
  const float* b1  = (const float*)d_in[24];
  const float* w2  = (const float*)d_in[25];
  const float* b2  = (const float*)d_in[26];

  float* ws   = (float*)d_ws;
  float* feat = ws;                        // 512*256
  float* xz   = feat + NTOK*DM;            // 512*1024
  float* xc   = xz   + NTOK*1024;          // 512*512
  float* dtv  = xc   + NTOK*DI;            // 512*512
  float* Bm   = dtv  + NTOK*DI;            // 512*16
  float* Cm   = Bm   + NTOK*16;            // 512*16
  float* yg   = Cm   + NTOK*16;            // 512*512
  (void)ws_size; (void)in_sizes; (void)n_in; (void)out_size;

  k_frontend<<<NTOK,256,0,stream>>>(x, ep, ef, ed, plw, plb, piw, pib, fw, fb, tg, tb, feat);
  for (int l = 0; l < 4; ++l){
    k_inproj<<<NTOK,256,0,stream>>>(feat, ipw + (size_t)l*1024*256, xz);
    k_conv<<<NTOK,512,0,stream>>>(xz, cw + (size_t)l*512*4, cb + (size_t)l*512,
                                  xpw + (size_t)l*48*512,
                                  dtw + (size_t)l*512*16, dtb + (size_t)l*512,
                                  xc, dtv, Bm, Cm);
    k_scan<<<32,256,0,stream>>>(dtv, xc, Bm, Cm, alog + (size_t)l*512*16,
                                dpr + (size_t)l*512, xz, yg);
    k_outln<<<NTOK,256,0,stream>>>(yg, opw + (size_t)l*256*512, ng, nb, feat);
  }
  k_cls<<<16,128,0,stream>>>(feat, w1, b1, w2, b2, (float*)d_out);
}

// Round 2
// 267.895 us; speedup vs baseline: 2.4275x; 2.4275x over previous
//
#include <hip/hip_runtime.h>
#include <cmath>

// BlockwiseEarlyExitMamba: output depends only on feat[:,31,:] -> compute T=32 tokens.
#define BATCH 16
#define TT 32
#define NTOK 512   // BATCH*TT
#define DM 256
#define DI 512

__device__ __forceinline__ float silu_(float x){ return x / (1.f + __expf(-x)); }

#define FMA16() do { \
  acc[0][0] += xv.x*wv.x; acc[0][1] += xv.x*wv.y; acc[0][2] += xv.x*wv.z; acc[0][3] += xv.x*wv.w; \
  acc[1][0] += xv.y*wv.x; acc[1][1] += xv.y*wv.y; acc[1][2] += xv.y*wv.z; acc[1][3] += xv.y*wv.w; \
  acc[2][0] += xv.z*wv.x; acc[2][1] += xv.z*wv.y; acc[2][2] += xv.z*wv.z; acc[2][3] += xv.z*wv.w; \
  acc[3][0] += xv.w*wv.x; acc[3][1] += xv.w*wv.y; acc[3][2] += xv.w*wv.z; acc[3][3] += xv.w*wv.w; \
} while(0)

// ---------- frontend: embed -> fusion GEMM (K=136) -> raw s0 -----------------
// grid (4 N-tiles, 16 batches), 128 thr, tile 32x64, thread 4x4
__global__ __launch_bounds__(128)
void k_front(const float* __restrict__ x,
             const float* __restrict__ ep, const float* __restrict__ ef,
             const float* __restrict__ ed,
             const float* __restrict__ plw, const float* __restrict__ plb,
             const float* __restrict__ piw, const float* __restrict__ pib,
             const float* __restrict__ fw,  const float* __restrict__ fb,
             float* __restrict__ s0)
{
  __shared__ float Xs[136*36];   // [k][t], stride 36
  __shared__ float Ws[136*68];   // [k][c], stride 68
  int bb = blockIdx.y;           // batch (M-tile of 32 tokens)
  int n0 = blockIdx.x*64;
  int tid = threadIdx.x;

  // stage cat on the fly: 136*32 elems, 34 per thread
  for (int r = 0; r < 34; ++r){
    int idx = r*128 + tid;
    int t = idx & 31, j = idx >> 5;
    const float* xr = x + ((size_t)(bb*1024 + t))*5;
    float v;
    if      (j <  32){ int i = __float2int_rz(xr[0]); i = min(max(i,0),255); v = ep[i*32 + j]; }
    else if (j <  64){ v = xr[1]*plw[j-32] + plb[j-32]; }
    else if (j <  96){ int i = __float2int_rz(xr[2]); i = min(max(i,0),63);  v = ef[i*32 + (j-64)]; }
    else if (j < 128){ v = xr[3]*piw[j-96] + pib[j-96]; }
    else             { int i = __float2int_rz(xr[4]); i = min(max(i,0),1);   v = ed[i*8 + (j-128)]; }
    Xs[j*36 + t] = v;
  }
  // stage W transposed: c = tid/2, jh = tid&1
  {
    int c = tid >> 1, jh = tid & 1;
    const float4* src = (const float4*)(fw + (size_t)(n0 + c)*136 + jh*68);
    #pragma unroll
    for (int q = 0; q < 17; ++q){
      float4 v = src[q];
      int j = jh*68 + q*4;
      Ws[(j+0)*68 + c] = v.x; Ws[(j+1)*68 + c] = v.y;
      Ws[(j+2)*68 + c] = v.z; Ws[(j+3)*68 + c] = v.w;
    }
  }
  __syncthreads();
  int my = tid >> 4, nx = tid & 15;
  float acc[4][4] = {};
  #pragma unroll 4
  for (int k = 0; k < 136; ++k){
    float4 xv = *(const float4*)&Xs[k*36 + my*4];
    float4 wv = *(const float4*)&Ws[k*68 + nx*4];
    FMA16();
  }
  #pragma unroll
  for (int i = 0; i < 4; ++i){
    int t = my*4 + i;
    float4 o;
    o.x = acc[i][0] + fb[n0 + nx*4 + 0];
    o.y = acc[i][1] + fb[n0 + nx*4 + 1];
    o.z = acc[i][2] + fb[n0 + nx*4 + 2];
    o.w = acc[i][3] + fb[n0 + nx*4 + 3];
    *(float4*)&s0[(size_t)(bb*32 + t)*DM + n0 + nx*4] = o;
  }
}

// ---------- residual sum (split-K parts) + LayerNorm -> feat -----------------
// grid 512 (token), 64 thr; p1..p3/base may be null
__global__ __launch_bounds__(64)
void k_rln(const float* __restrict__ p0, const float* __restrict__ p1,
           const float* __restrict__ p2, const float* __restrict__ p3,
           const float* __restrict__ base,
           const float* __restrict__ g, const float* __restrict__ b,
           float* __restrict__ feat)
{
  int p = blockIdx.x, tid = threadIdx.x;
  size_t off = (size_t)p*DM + tid*4;
  float4 v = *(const float4*)&p0[off];
  if (p1){ float4 a = *(const float4*)&p1[off]; v.x+=a.x; v.y+=a.y; v.z+=a.z; v.w+=a.w; }
  if (p2){ float4 a = *(const float4*)&p2[off]; v.x+=a.x; v.y+=a.y; v.z+=a.z; v.w+=a.w; }
  if (p3){ float4 a = *(const float4*)&p3[off]; v.x+=a.x; v.y+=a.y; v.z+=a.z; v.w+=a.w; }
  if (base){ float4 a = *(const float4*)&base[off]; v.x+=a.x; v.y+=a.y; v.z+=a.z; v.w+=a.w; }
  float s  = v.x + v.y + v.z + v.w;
  float sq = v.x*v.x + v.y*v.y + v.z*v.z + v.w*v.w;
  #pragma unroll
  for (int o = 1; o < 64; o <<= 1){ s += __shfl_xor(s, o, 64); sq += __shfl_xor(sq, o, 64); }
  float mu = s * (1.f/256.f);
  float var = sq * (1.f/256.f) - mu*mu;
  float r = rsqrtf(var + 1e-5f);
  float4 gg = *(const float4*)&g[tid*4];
  float4 bb = *(const float4*)&b[tid*4];
  float4 o;
  o.x = (v.x-mu)*r*gg.x + bb.x;
  o.y = (v.y-mu)*r*gg.y + bb.y;
  o.z = (v.z-mu)*r*gg.z + bb.z;
  o.w = (v.w-mu)*r*gg.w + bb.w;
  *(float4*)&feat[off] = o;
}

// ---------- in_proj GEMM: xz[512][1024] = feat[512][256] @ ipw^T -------------
// grid (16 N-tiles, 16 M-tiles), 128 thr, tile 32x64, full-K staged
__global__ __launch_bounds__(128)
void k_inproj(const float* __restrict__ feat, const float* __restrict__ w,
              float* __restrict__ xz)
{
  __shared__ float Xs[256*36];
  __shared__ float Ws[64*68];
  int m0 = blockIdx.y*32, n0 = blockIdx.x*64;
  int tid = threadIdx.x;
  {
    int t = tid >> 2, kq = tid & 3;
    const float4* src = (const float4*)(feat + (size_t)(m0+t)*DM + kq*64);
    #pragma unroll
    for (int q = 0; q < 16; ++q){
      float4 v = src[q];
      int k = kq*64 + q*4;
      Xs[(k+0)*36+t]=v.x; Xs[(k+1)*36+t]=v.y; Xs[(k+2)*36+t]=v.z; Xs[(k+3)*36+t]=v.w;
    }
  }
  int my = tid >> 4, nx = tid & 15;
  float acc[4][4] = {};
  for (int kc = 0; kc < 256; kc += 64){
    __syncthreads();
    {
      int c = tid >> 1, kh = tid & 1;
      const float4* src = (const float4*)(w + (size_t)(n0+c)*DM + kc + kh*32);
      #pragma unroll
      for (int q = 0; q < 8; ++q){
        float4 v = src[q];
        int k = kh*32 + q*4;
        Ws[(k+0)*68+c]=v.x; Ws[(k+1)*68+c]=v.y; Ws[(k+2)*68+c]=v.z; Ws[(k+3)*68+c]=v.w;
      }
    }
    __syncthreads();
    #pragma unroll 4
    for (int kk = 0; kk < 64; ++kk){
      float4 xv = *(const float4*)&Xs[(kc+kk)*36 + my*4];
      float4 wv = *(const float4*)&Ws[kk*68 + nx*4];
      FMA16();
    }
  }
  #pragma unroll
  for (int i = 0; i < 4; ++i){
    float4 o = {acc[i][0], acc[i][1], acc[i][2], acc[i][3]};
    *(float4*)&xz[(size_t)(m0 + my*4 + i)*1024 + n0 + nx*4] = o;
  }
}

// ---------- conv + silu -> xc ; x_proj (wave-split) ; dt softplus ------------
// grid 512 (token), 512 thr
__global__ __launch_bounds__(512)
void k_conv(const float* __restrict__ xz,
            const float* __restrict__ cw, const float* __restrict__ cb,
            const float* __restrict__ xpw,
            const float* __restrict__ dtw, const float* __restrict__ dtb,
            float* __restrict__ xc, float* __restrict__ dtv,
            float* __restrict__ Bm, float* __restrict__ Cm)
{
  __shared__ float sxc[512];
  __shared__ float sdtr[16];
  __shared__ float sdtw[512*17];
  int p = blockIdx.x; int b = p >> 5, t = p & 31;
  int d = threadIdx.x;
  {
    const float4* src = (const float4*)(dtw + (size_t)d*16);
    #pragma unroll
    for (int q = 0; q < 4; ++q){
      float4 v = src[q]; int r = q*4;
      sdtw[d*17+r]=v.x; sdtw[d*17+r+1]=v.y; sdtw[d*17+r+2]=v.z; sdtw[d*17+r+3]=v.w;
    }
  }
  float a = cb[d];
  const float* cwr = cw + d*4;
  #pragma unroll
  for (int k = 0; k < 4; ++k){
    int tt = t - 3 + k;
    if (tt >= 0) a += cwr[k] * xz[((size_t)(b*TT + tt))*1024 + d];
  }
  float v = silu_(a);
  sxc[d] = v;
  xc[(size_t)p*DI + d] = v;
  __syncthreads();
  // x_proj: 8 waves x 6 channels, lane-split K=512 (stride-64), shuffle reduce
  int wv_ = d >> 6, ln = d & 63;
  #pragma unroll
  for (int i = 0; i < 6; ++i){
    int c = wv_*6 + i;
    const float* wr = xpw + (size_t)c*512;
    float pa = 0.f;
    #pragma unroll
    for (int j = 0; j < 8; ++j) pa += wr[ln + 64*j] * sxc[ln + 64*j];
    #pragma unroll
    for (int o = 32; o; o >>= 1) pa += __shfl_down(pa, o, 64);
    if (ln == 0){
      if      (c < 16) sdtr[c] = pa;
      else if (c < 32) Bm[(size_t)p*16 + (c-16)] = pa;
      else             Cm[(size_t)p*16 + (c-32)] = pa;
    }
  }
  __syncthreads();
  float aa = dtb[d];
  #pragma unroll
  for (int r = 0; r < 16; ++r) aa += sdtr[r]*sdtw[d*17+r];
  dtv[(size_t)p*DI + d] = fmaxf(aa, 0.f) + log1pf(expf(-fabsf(aa)));
}

// ---------- selective scan + D-skip -> y (pre-gate) --------------------------
// grid 128 = (16 b x 8 d-slices of 64), 64 thr; dt/x staged in LDS, B/C uniform
__global__ __launch_bounds__(64)
void k_scan(const float* __restrict__ dtv, const float* __restrict__ xc,
            const float* __restrict__ Bm, const float* __restrict__ Cm,
            const float* __restrict__ alog, const float* __restrict__ dprm,
            float* __restrict__ y)
{
  __shared__ float sdt[32*65], sxv[32*65];
  int b = blockIdx.x >> 3, dq = blockIdx.x & 7;
  int d0 = dq*64, ln = threadIdx.x;
  {
    int t = ln >> 1, h = ln & 1;
    const float4* s1 = (const float4*)(dtv + ((size_t)(b*TT + t))*DI + d0 + h*32);
    const float4* s2 = (const float4*)(xc  + ((size_t)(b*TT + t))*DI + d0 + h*32);
    #pragma unroll
    for (int q = 0; q < 8; ++q){
      float4 v = s1[q]; int j = h*32 + q*4;
      sdt[t*65+j]=v.x; sdt[t*65+j+1]=v.y; sdt[t*65+j+2]=v.z; sdt[t*65+j+3]=v.w;
      float4 u = s2[q];
      sxv[t*65+j]=u.x; sxv[t*65+j+1]=u.y; sxv[t*65+j+2]=u.z; sxv[t*65+j+3]=u.w;
    }
  }
  int d = d0 + ln;
  float A[16], hh[16];
  {
    const float4* as = (const float4*)(alog + (size_t)d*16);
    #pragma unroll
    for (int q = 0; q < 4; ++q){
      float4 v = as[q];
      A[q*4+0] = -expf(v.x); A[q*4+1] = -expf(v.y);
      A[q*4+2] = -expf(v.z); A[q*4+3] = -expf(v.w);
      hh[q*4+0]=0.f; hh[q*4+1]=0.f; hh[q*4+2]=0.f; hh[q*4+3]=0.f;
    }
  }
  float Dp = dprm[d];
  __syncthreads();
  for (int t = 0; t < TT; ++t){
    float dt = sdt[t*65 + ln], xv = sxv[t*65 + ln];
    float dx = dt*xv;
    const float* Bp = Bm + ((size_t)(b*TT + t))*16;
    const float* Cp = Cm + ((size_t)(b*TT + t))*16;
    float yv = Dp*xv;
    #pragma unroll
    for (int n = 0; n < 16; ++n){
      hh[n] = __expf(dt*A[n])*hh[n] + dx*Bp[n];
      yv += hh[n]*Cp[n];
    }
    y[((size_t)(b*TT + t))*DI + d] = yv;
  }
}

// ---------- out_proj split-K GEMM with fused gate: parts[kz] = (y*silu(z)) @ opw^T
// grid (4 N-tiles, 16 M-tiles, 4 K-chunks), 128 thr, tile 32x64, K-chunk 128
__global__ __launch_bounds__(128)
void k_outproj(const float* __restrict__ y, const float* __restrict__ xz,
               const float* __restrict__ w, float* __restrict__ parts)
{
  __shared__ float Xs[128*36];
  __shared__ float Ws[128*68];
  int n0 = blockIdx.x*64, m0 = blockIdx.y*32, kz = blockIdx.z;
  int k0 = kz*128;
  int tid = threadIdx.x;
  {
    int t = tid >> 2, kq = tid & 3;
    const float4* sy = (const float4*)(y  + (size_t)(m0+t)*DI   + k0 + kq*32);
    const float4* sz = (const float4*)(xz + (size_t)(m0+t)*1024 + 512 + k0 + kq*32);
    #pragma unroll
    for (int q = 0; q < 8; ++q){
      float4 a = sy[q], zz = sz[q];
      int k = kq*32 + q*4;
      Xs[(k+0)*36+t] = a.x*silu_(zz.x);
      Xs[(k+1)*36+t] = a.y*silu_(zz.y);
      Xs[(k+2)*36+t] = a.z*silu_(zz.z);
      Xs[(k+3)*36+t] = a.w*silu_(zz.w);
    }
  }
  {
    int c = tid >> 1, kh = tid & 1;
    const float4* src = (const float4*)(w + (size_t)(n0+c)*DI + k0 + kh*64);
    #pragma unroll
    for (int q = 0; q < 16; ++q){
      float4 v = src[q];
      int k = kh*64 + q*4;
      Ws[(k+0)*68+c]=v.x; Ws[(k+1)*68+c]=v.y; Ws[(k+2)*68+c]=v.z; Ws[(k+3)*68+c]=v.w;
    }
  }
  __syncthreads();
  int my = tid >> 4, nx = tid & 15;
  float acc[4][4] = {};
  #pragma unroll 4
  for (int kk = 0; kk < 128; ++kk){
    float4 xv = *(const float4*)&Xs[kk*36 + my*4];
    float4 wv = *(const float4*)&Ws[kk*68 + nx*4];
    FMA16();
  }
  float* dst = parts + (size_t)kz*NTOK*DM;
  #pragma unroll
  for (int i = 0; i < 4; ++i){
    float4 o = {acc[i][0], acc[i][1], acc[i][2], acc[i][3]};
    *(float4*)&dst[(size_t)(m0 + my*4 + i)*DM + n0 + nx*4] = o;
  }
}

// ---------- classifier on token 31 ------------------------------------------
__global__ __launch_bounds__(128)
void k_cls(const float* __restrict__ feat,
           const float* __restrict__ w1, const float* __restrict__ b1,
           const float* __restrict__ w2, const float* __restrict__ b2,
           float* __restrict__ out)
{
  __shared__ float h[256];
  __shared__ float h1[128];
  int b = blockIdx.x;
  int tid = threadIdx.x;
  const float* fr = feat + ((size_t)(b*TT + 31))*DM;
  h[tid]       = fr[tid];
  h[tid + 128] = fr[tid + 128];
  __syncthreads();
  float a = b1[tid];
  const float* wr = w1 + (size_t)tid*256;
  #pragma unroll 8
  for (int j = 0; j < 256; ++j) a += h[j]*wr[j];
  h1[tid] = fmaxf(a, 0.f);
  __syncthreads();
  if (tid < 2){
    float a2 = b2[tid];
    const float* wr2 = w2 + (size_t)tid*128;
    #pragma unroll 8
    for (int j = 0; j < 128; ++j) a2 += h1[j]*wr2[j];
    out[b*2 + tid] = a2;
  }
}

extern "C" void kernel_launch(void* const* d_in, const int* in_sizes, int n_in,
                              void* d_out, int out_size, void* d_ws, size_t ws_size,
                              hipStream_t stream)
{
  const float* x   = (const float*)d_in[0];
  const float* ep  = (const float*)d_in[1];
  const float* ef  = (const float*)d_in[2];
  const float* ed  = (const float*)d_in[3];
  const float* plw = (const float*)d_in[4];
  const float* plb = (const float*)d_in[5];
  const float* piw = (const float*)d_in[6];
  const float* pib = (const float*)d_in[7];
  const float* fw  = (const float*)d_in[8];
  const float* fb  = (const float*)d_in[9];
  const float* tg  = (const float*)d_in[10];
  const float* tb  = (const float*)d_in[11];
  const float* ng  = (const float*)d_in[12];
  const float* nb  = (const float*)d_in[13];
  const float* ipw = (const float*)d_in[14];
  const float* cw  = (const float*)d_in[15];
  const float* cb  = (const float*)d_in[16];
  const float* xpw = (const float*)d_in[17];
  const float* dtw = (const float*)d_in[18];
  const float* dtb = (const float*)d_in[19];
  const float* alog= (const float*)d_in[20];
  const float* dpr = (const float*)d_in[21];
  const float* opw = (const float*)d_in[22];
  const float* w1  = (const float*)d_in[23];
  const float* b1  = (const float*)d_in[24];
  const float* w2  = (const float*)d_in[25];
  const float* b2  = (const float*)d_in[26];

  float* ws   = (float*)d_ws;
  float* feat = ws;                       // 131072
  float* xz   = feat + NTOK*DM;           // 524288
  float* xcdt = xz + NTOK*1024;           // 524288 region: xc|dtv, aliased by parts
  float* xc   = xcdt;
  float* dtv  = xc + NTOK*DI;
  float* parts= xcdt;                     // alias (safe: parts written after xc/dtv consumed)
  float* Bm   = xcdt + 2*(size_t)NTOK*DI; // 8192
  float* Cm   = Bm + NTOK*16;             // 8192
  float* y    = Cm + NTOK*16;             // 262144
  (void)ws_size; (void)in_sizes; (void)n_in; (void)out_size;

  const size_t PS = (size_t)NTOK*DM;

  // frontend: raw fusion out -> parts[0]; then token-LN -> feat
  k_front<<<dim3(4,16),128,0,stream>>>(x, ep,ef,ed, plw,plb,piw,pib, fw,fb, parts);
  k_rln<<<NTOK,64,0,stream>>>(parts, nullptr,nullptr,nullptr, nullptr, tg, tb, feat);

  for (int l = 0; l < 4; ++l){
    k_inproj<<<dim3(16,16),128,0,stream>>>(feat, ipw + (size_t)l*1024*256, xz);
    k_conv<<<NTOK,512,0,stream>>>(xz, cw + (size_t)l*512*4, cb + (size_t)l*512,
                                  xpw + (size_t)l*48*512,
                                  dtw + (size_t)l*512*16, dtb + (size_t)l*512,
                                  xc, dtv, Bm, Cm);
    k_scan<<<128,64,0,stream>>>(dtv, xc, Bm, Cm, alog + (size_t)l*512*16,
                                dpr + (size_t)l*512, y);
    k_outproj<<<dim3(4,16,4),128,0,stream>>>(y, xz, opw + (size_t)l*256*512, parts);
    k_rln<<<NTOK,64,0,stream>>>(parts, parts+PS, parts+2*PS, parts+3*PS,
                                feat, ng, nb, feat);
  }
  k_cls<<<BATCH,128,0,stream>>>(feat, w1, b1, w2, b2, (float*)d_out);
}